// Round 6
// baseline (1383.968 us; speedup 1.0000x reference)
//
#include <hip/hip_runtime.h>

#define NN 50000
#define NE 600000
#define IND 64
#define HID 128
#define NREL 10
#define NLAY 6
#define NG 64
#define LN_EPS 1e-5f

typedef __attribute__((ext_vector_type(8))) short bf8;
typedef __attribute__((ext_vector_type(4))) float f4;

__device__ __forceinline__ ushort f2bf(float x) {
  uint u = __float_as_uint(x);
  u += 0x7fff + ((u >> 16) & 1);
  return (ushort)(u >> 16);
}
__device__ __forceinline__ float bf2f(ushort h) {
  return __uint_as_float(((uint)h) << 16);
}

// ---------------------------------------------------------------- utilities
__global__ void zero_kernel(float* __restrict__ p, int n) {
  int i = blockIdx.x * blockDim.x + threadIdx.x;
  int stride = gridDim.x * blockDim.x;
  for (; i < n; i += stride) p[i] = 0.f;
}

__global__ void count_edges(const int* __restrict__ dst, const int* __restrict__ et,
                            float* __restrict__ winv, int* __restrict__ deg) {
  int e = blockIdx.x * 256 + threadIdx.x;
  if (e >= NE) return;
  int d = dst[e];
  atomicAdd(&winv[d * NREL + et[e]], 1.0f);
  atomicAdd(&deg[d], 1);
}

__global__ void invert_winv(float* __restrict__ winv) {
  int i = blockIdx.x * 256 + threadIdx.x;
  if (i < NN * NREL) winv[i] = 1.0f / fmaxf(winv[i], 1.0f);
}

__global__ void scan_block(const int* __restrict__ deg, int* __restrict__ rowstart,
                           int* __restrict__ partial) {
  __shared__ int sh[256];
  int i = blockIdx.x * 256 + threadIdx.x;
  int v = (i < NN) ? deg[i] : 0;
  sh[threadIdx.x] = v;
  __syncthreads();
  int x = v;
  for (int off = 1; off < 256; off <<= 1) {
    int y = (threadIdx.x >= off) ? sh[threadIdx.x - off] : 0;
    __syncthreads();
    x += y;
    sh[threadIdx.x] = x;
    __syncthreads();
  }
  if (i < NN) rowstart[i] = x - v;
  if (threadIdx.x == 255) partial[blockIdx.x] = x;
}

__global__ void scan_partials(int* __restrict__ partial, int nb) {
  __shared__ int sh[256];
  int v = (threadIdx.x < nb) ? partial[threadIdx.x] : 0;
  sh[threadIdx.x] = v;
  __syncthreads();
  int x = v;
  for (int off = 1; off < 256; off <<= 1) {
    int y = (threadIdx.x >= off) ? sh[threadIdx.x - off] : 0;
    __syncthreads();
    x += y;
    sh[threadIdx.x] = x;
    __syncthreads();
  }
  partial[threadIdx.x] = x - v;
}

__global__ void scan_add(int* __restrict__ rowstart, const int* __restrict__ partial) {
  int i = blockIdx.x * 256 + threadIdx.x;
  if (i < NN) rowstart[i] += partial[i >> 8];
  if (i == 0) rowstart[NN] = NE;
}

// CSR fill: packed (src<<4|type) and per-edge scale winv[dst,type]
__global__ void fill_csr(const int* __restrict__ dst, const int* __restrict__ src,
                         const int* __restrict__ et, int* __restrict__ fillpos,
                         const int* __restrict__ rowstart, const float* __restrict__ winv,
                         int* __restrict__ pkd, float* __restrict__ wsc) {
  int e = blockIdx.x * 256 + threadIdx.x;
  if (e >= NE) return;
  int d = dst[e], t = et[e];
  int pos = rowstart[d] + atomicAdd(&fillpos[d], 1);
  pkd[pos] = (src[e] << 4) | t;
  wsc[pos] = winv[d * NREL + t];
}

// ------------------------------------------------------------- weight prep
// Wp [K][128] fp32 -> fragment-linear bf16 hi/lo (transposed: stored[n][k])
__global__ void transpose_split_frag(const float* __restrict__ src, ushort* __restrict__ dh,
                                     ushort* __restrict__ dl, int K) {
  int i = blockIdx.x * 256 + threadIdx.x;
  int tot = K * 128;
  if (i >= tot) return;
  int k = i / 128;
  int n = i - k * 128;
  float v = src[i];
  ushort h = f2bf(v);
  size_t o = (size_t)(n >> 4) * (K * 16) + (k >> 3) * 128 + (n & 15) * 8 + (k & 7);
  dh[o] = h;
  dl[o] = f2bf(v - bf2f(h));
}

// Pack per-layer big-B (K=1536): B1=[root_h; root_h; W1_h..W10_h], B2=[root_l; 0; W_l]
// fragment-linear stored[n][k]: off = (n>>4)*24576 + (k>>3)*128 + (n&15)*8 + (k&7)
__global__ void pack_B(const float* __restrict__ root_w, const float* __restrict__ rel_w,
                       ushort* __restrict__ Bp) {
  int i = blockIdx.x * 256 + threadIdx.x;
  const int tot = NLAY * 1536 * 128;
  if (i >= tot) return;
  int l = i / (1536 * 128);
  int rem = i - l * (1536 * 128);
  int k = rem >> 7;
  int n = rem & 127;
  ushort s1, s2;
  if (k < 128) {
    float v = root_w[(size_t)l * 16384 + k * 128 + n];
    s1 = f2bf(v);
    s2 = f2bf(v - bf2f(s1));
  } else if (k < 256) {
    float v = root_w[(size_t)l * 16384 + (k - 128) * 128 + n];
    s1 = f2bf(v);
    s2 = 0;
  } else {
    int r = (k - 256) >> 7, kk = (k - 256) & 127;
    float v = rel_w[(((size_t)l * NREL + r) * 128 + kk) * 128 + n];
    s1 = f2bf(v);
    s2 = f2bf(v - bf2f(s1));
  }
  size_t off = (size_t)(n >> 4) * 24576 + (k >> 3) * 128 + (n & 15) * 8 + (k & 7);
  size_t base = (size_t)l * 2 * 196608;
  Bp[base + off] = s1;
  Bp[base + 196608 + off] = s2;
}

// rows fp32 [N][K] -> fragment-linear bf16 hi/lo (+optional linear bf16 copy)
template <int K>
__global__ __launch_bounds__(256) void split_frag(const float* __restrict__ src,
                                                  ushort* __restrict__ dh,
                                                  ushort* __restrict__ dl,
                                                  ushort* __restrict__ db) {
  constexpr int TOT = 16 * K;
  __shared__ ushort sh[TOT], sl[TOT];
  int grp = blockIdx.x;
  const float* s = src + (size_t)grp * TOT;
  for (int i = threadIdx.x * 4; i < TOT; i += 1024) {
    float4 v = *(const float4*)(s + i);
    int nl = i / K, d = i - nl * K;
    int off = (d >> 3) * 128 + nl * 8 + (d & 7);
    ushort h0 = f2bf(v.x), h1 = f2bf(v.y), h2 = f2bf(v.z), h3 = f2bf(v.w);
    *(uint*)(sh + off) = (uint)h0 | ((uint)h1 << 16);
    *(uint*)(sh + off + 2) = (uint)h2 | ((uint)h3 << 16);
    *(uint*)(sl + off) = (uint)f2bf(v.x - bf2f(h0)) | ((uint)f2bf(v.y - bf2f(h1)) << 16);
    *(uint*)(sl + off + 2) = (uint)f2bf(v.z - bf2f(h2)) | ((uint)f2bf(v.w - bf2f(h3)) << 16);
    if (db) {
      uint2 pk;
      pk.x = (uint)h0 | ((uint)h1 << 16);
      pk.y = (uint)h2 | ((uint)h3 << 16);
      *(uint2*)(db + (size_t)(grp * 16 + nl) * K + d) = pk;
    }
  }
  __syncthreads();
  size_t base = (size_t)grp * TOT;
  for (int i = threadIdx.x * 8; i < TOT; i += 2048) {
    *(bf8*)(dh + base + i) = *(const bf8*)(sh + i);
    *(bf8*)(dl + base + i) = *(const bf8*)(sl + i);
  }
}

// ------------------------------------------- projection GEMM (3-term, K=64)
struct Frags {
  bf8 ah[4], al[4], bh[4], bl[4];
};

template <int K>
__device__ __forceinline__ void load_frags(Frags& f, int ks, const ushort* Abh,
                                           const ushort* Abl, const ushort* Bbh,
                                           const ushort* Bbl) {
#pragma unroll
  for (int m = 0; m < 4; ++m) {
    f.ah[m] = *(const bf8*)(Abh + (size_t)m * (K * 16) + ks * 512);
    f.al[m] = *(const bf8*)(Abl + (size_t)m * (K * 16) + ks * 512);
  }
#pragma unroll
  for (int n = 0; n < 4; ++n) {
    f.bh[n] = *(const bf8*)(Bbh + (size_t)n * (K * 16) + ks * 512);
    f.bl[n] = *(const bf8*)(Bbl + (size_t)n * (K * 16) + ks * 512);
  }
}

__device__ __forceinline__ void mfma_frags(f4 (&acc)[4][4], const Frags& f) {
#pragma unroll
  for (int m = 0; m < 4; ++m)
#pragma unroll
    for (int n = 0; n < 4; ++n) {
      acc[m][n] = __builtin_amdgcn_mfma_f32_16x16x32_bf16(f.ah[m], f.bh[n], acc[m][n], 0, 0, 0);
      acc[m][n] = __builtin_amdgcn_mfma_f32_16x16x32_bf16(f.al[m], f.bh[n], acc[m][n], 0, 0, 0);
      acc[m][n] = __builtin_amdgcn_mfma_f32_16x16x32_bf16(f.ah[m], f.bl[n], acc[m][n], 0, 0, 0);
    }
}

template <int K>
__global__ __launch_bounds__(256) void gemm_frag(
    const ushort* __restrict__ Ah, const ushort* __restrict__ Al,
    const ushort* __restrict__ Bh, const ushort* __restrict__ Bl,
    const float* __restrict__ bias, float* __restrict__ Cf, int M) {
  const int bm = blockIdx.y * 128;
  const int tid = threadIdx.x, w = tid >> 6, lane = tid & 63;
  const int wr = (w >> 1) * 64, wc = (w & 1) * 64;
  const int lr = lane & 15;

  const ushort* Abh = Ah + ((size_t)(bm >> 4) + (wr >> 4)) * (K * 16) + lane * 8;
  const ushort* Abl = Al + ((size_t)(bm >> 4) + (wr >> 4)) * (K * 16) + lane * 8;
  const ushort* Bbh = Bh + (size_t)(wc >> 4) * (K * 16) + lane * 8;
  const ushort* Bbl = Bl + (size_t)(wc >> 4) * (K * 16) + lane * 8;

  f4 acc[4][4] = {};
  Frags fa, fb;
  load_frags<K>(fa, 0, Abh, Abl, Bbh, Bbl);
  load_frags<K>(fb, 1, Abh, Abl, Bbh, Bbl);
  mfma_frags(acc, fa);
  mfma_frags(acc, fb);

  const int rgrp = (lane >> 4) * 4;
#pragma unroll
  for (int n = 0; n < 4; ++n) {
    int col = wc + n * 16 + lr;
    float bv = bias[col];
#pragma unroll
    for (int m = 0; m < 4; ++m) {
      int r0 = bm + wr + m * 16 + rgrp;
#pragma unroll
      for (int j = 0; j < 4; ++j) {
        int r = r0 + j;
        if (r < M) Cf[(size_t)r * 128 + col] = acc[m][n][j] + bv;
      }
    }
  }
}

// ----------------------------- per-(node,rel) mean aggregation into AGG bf16
// One wave per 4 nodes; predicated static acc[10][2]; fragment-linear output
// staged in LDS for coalesced 16B stores.
__global__ __launch_bounds__(256) void agg2(
    const int* __restrict__ pkd, const float* __restrict__ wsc,
    const int* __restrict__ rowstart, const ushort* __restrict__ hb,
    ushort* __restrict__ AGG) {
  __shared__ ushort st[16][1288];  // +8 pad: row stride 2576B -> bank spread
  const int grp = blockIdx.x;
  const int w = threadIdx.x >> 6, lane = threadIdx.x & 63;
#pragma unroll
  for (int p4 = 0; p4 < 4; ++p4) {
    const int row = w * 4 + p4;
    const int node = grp * 16 + row;
    float ac[NREL][2];
#pragma unroll
    for (int r = 0; r < NREL; ++r) {
      ac[r][0] = 0.f;
      ac[r][1] = 0.f;
    }
    const int e1 = rowstart[node + 1];
    int p = rowstart[node];
    constexpr int U = 8;
    for (; p + U <= e1; p += U) {
      int pk[U];
      float wg[U];
      uint v[U];
#pragma unroll
      for (int u = 0; u < U; ++u) {
        pk[u] = pkd[p + u];
        wg[u] = wsc[p + u];
      }
#pragma unroll
      for (int u = 0; u < U; ++u)
        v[u] = *(const uint*)(hb + (size_t)(pk[u] >> 4) * HID + lane * 2);
#pragma unroll
      for (int u = 0; u < U; ++u) {
        float vx = wg[u] * bf2f((ushort)(v[u] & 0xffffu));
        float vy = wg[u] * bf2f((ushort)(v[u] >> 16));
        int t = pk[u] & 15;
#pragma unroll
        for (int r = 0; r < NREL; ++r) {
          if (t == r) {
            ac[r][0] += vx;
            ac[r][1] += vy;
          }
        }
      }
    }
    for (; p < e1; ++p) {
      int pk = pkd[p];
      float wg = wsc[p];
      uint v = *(const uint*)(hb + (size_t)(pk >> 4) * HID + lane * 2);
      float vx = wg * bf2f((ushort)(v & 0xffffu));
      float vy = wg * bf2f((ushort)(v >> 16));
      int t = pk & 15;
#pragma unroll
      for (int r = 0; r < NREL; ++r) {
        if (t == r) {
          ac[r][0] += vx;
          ac[r][1] += vy;
        }
      }
    }
#pragma unroll
    for (int r = 0; r < NREL; ++r)
      *(uint*)&st[row][r * HID + lane * 2] =
          (uint)f2bf(ac[r][0]) | ((uint)f2bf(ac[r][1]) << 16);
  }
  __syncthreads();
  size_t base = (size_t)grp * 20480;
#pragma unroll
  for (int it = 0; it < 10; ++it) {
    int o = it * 2048 + threadIdx.x * 8;
    int chunk = o >> 7, rw = (o >> 3) & 15;
    *(bf8*)(AGG + base + o) = *(const bf8*)&st[rw][chunk * 8];
  }
}

// ---------------------- big-K GEMM: OUT = [hh|hl|AGG] @ (B1 + B2) + bias
// BM=64, N=128, 4 waves 2x2, wave tile 32x64. K=1536 (8+8 chunks h, 160 AGG).
__device__ __forceinline__ void g2_step(f4 (&acc)[2][4], const ushort* Ap, size_t mstride,
                                        int aoff, const ushort* B1, const ushort* B2,
                                        int boff) {
  bf8 a[2], b1[4], b2[4];
#pragma unroll
  for (int m = 0; m < 2; ++m) a[m] = *(const bf8*)(Ap + m * mstride + aoff);
#pragma unroll
  for (int n = 0; n < 4; ++n) {
    b1[n] = *(const bf8*)(B1 + n * 24576 + boff);
    b2[n] = *(const bf8*)(B2 + n * 24576 + boff);
  }
#pragma unroll
  for (int m = 0; m < 2; ++m)
#pragma unroll
    for (int n = 0; n < 4; ++n) {
      acc[m][n] = __builtin_amdgcn_mfma_f32_16x16x32_bf16(a[m], b1[n], acc[m][n], 0, 0, 0);
      acc[m][n] = __builtin_amdgcn_mfma_f32_16x16x32_bf16(a[m], b2[n], acc[m][n], 0, 0, 0);
    }
}

__global__ __launch_bounds__(256) void gemm2(
    const ushort* __restrict__ Ahh, const ushort* __restrict__ Ahl,
    const ushort* __restrict__ AGG, const ushort* __restrict__ Bp,
    const float* __restrict__ bias, float* __restrict__ OUT, int M) {
  const int bm = blockIdx.x * 64;
  const int tid = threadIdx.x, w = tid >> 6, lane = tid & 63;
  const int wrg = (w >> 1) * 2;  // A 16-row-group offset within block
  const int wc = (w & 1) * 64;
  const int agrp = (bm >> 4) + wrg;
  const ushort* pA0 = Ahh + (size_t)agrp * 2048 + lane * 8;
  const ushort* pA1 = Ahl + (size_t)agrp * 2048 + lane * 8;
  const ushort* pA2 = AGG + (size_t)agrp * 20480 + lane * 8;
  const ushort* pB1 = Bp + (size_t)(wc >> 4) * 24576 + lane * 8;
  const ushort* pB2 = pB1 + 196608;

  f4 acc[2][4] = {};
#pragma unroll
  for (int ks = 0; ks < 4; ++ks) g2_step(acc, pA0, 2048, ks * 512, pB1, pB2, ks * 512);
#pragma unroll
  for (int ks = 0; ks < 4; ++ks) g2_step(acc, pA1, 2048, ks * 512, pB1, pB2, (4 + ks) * 512);
#pragma unroll
  for (int ks = 0; ks < 40; ++ks) g2_step(acc, pA2, 20480, ks * 512, pB1, pB2, (8 + ks) * 512);

  const int rgrp = (lane >> 4) * 4;
#pragma unroll
  for (int n = 0; n < 4; ++n) {
    int col = wc + n * 16 + (lane & 15);
    float bv = bias[col];
#pragma unroll
    for (int m = 0; m < 2; ++m) {
      int r0 = bm + (wrg + m) * 16 + rgrp;
#pragma unroll
      for (int j = 0; j < 4; ++j) {
        int r = r0 + j;
        if (r < M) OUT[(size_t)r * 128 + col] = acc[m][n][j] + bv;
      }
    }
  }
}

// ------------------- LN + ReLU + residual (+ bf16 split + linear bf16 copy)
__global__ __launch_bounds__(256) void ln2(
    const float* __restrict__ OUT, float* __restrict__ h,
    const float* __restrict__ g, const float* __restrict__ b,
    ushort* __restrict__ dh, ushort* __restrict__ dl, ushort* __restrict__ db,
    int writeSplit) {
  __shared__ ushort sh[2048], sl[2048];
  int grp = blockIdx.x;
  int w = threadIdx.x >> 6, lane = threadIdx.x & 63;
  int lo = lane * 2;
  float2 gg = *(const float2*)(g + lo);
  float2 bb = *(const float2*)(b + lo);
#pragma unroll
  for (int p = 0; p < 4; ++p) {
    int r = w * 4 + p;
    int node = grp * 16 + r;
    float2 v = *(const float2*)(OUT + (size_t)node * HID + lo);
    float s = v.x + v.y, sq = v.x * v.x + v.y * v.y;
#pragma unroll
    for (int off = 32; off; off >>= 1) {
      s += __shfl_xor(s, off);
      sq += __shfl_xor(sq, off);
    }
    float mu = s * (1.f / HID);
    float var = sq * (1.f / HID) - mu * mu;
    float rs = rsqrtf(var + LN_EPS);
    float2 rr = *(const float2*)(h + (size_t)node * HID + lo);
    float y0 = fmaxf((v.x - mu) * rs * gg.x + bb.x, 0.f) + rr.x;
    float y1 = fmaxf((v.y - mu) * rs * gg.y + bb.y, 0.f) + rr.y;
    *(float2*)(h + (size_t)node * HID + lo) = make_float2(y0, y1);
    if (writeSplit) {
      ushort h0 = f2bf(y0), h1 = f2bf(y1);
      int off2 = (lo >> 3) * 128 + r * 8 + (lo & 7);
      *(uint*)(sh + off2) = (uint)h0 | ((uint)h1 << 16);
      *(uint*)(sl + off2) = (uint)f2bf(y0 - bf2f(h0)) | ((uint)f2bf(y1 - bf2f(h1)) << 16);
      *(uint*)(db + (size_t)node * HID + lo) = (uint)h0 | ((uint)h1 << 16);
    }
  }
  __syncthreads();
  if (writeSplit) {
    size_t base = (size_t)grp * 2048;
    int t8 = threadIdx.x * 8;
    *(bf8*)(dh + base + t8) = *(const bf8*)(sh + t8);
    *(bf8*)(dl + base + t8) = *(const bf8*)(sl + t8);
  }
}

// ---------------------------------------------------------------- pooling
__global__ void pool_kernel(const float* __restrict__ h, const int* __restrict__ batch,
                            float* __restrict__ out) {
  int n0 = blockIdx.x * 64;
  if (n0 >= NN) return;
  int t = threadIdx.x;
  int nend = min(n0 + 64, NN);
  int cur = batch[n0];
  float acc = 0.f;
  for (int n = n0; n < nend; ++n) {
    int gph = batch[n];
    if (gph != cur) {
      atomicAdd(&out[cur * HID + t], acc);
      acc = 0.f;
      cur = gph;
    }
    acc += h[(size_t)n * HID + t];
  }
  atomicAdd(&out[cur * HID + t], acc);
}

// ---------------------------------------------------------------- launch
extern "C" void kernel_launch(void* const* d_in, const int* in_sizes, int n_in,
                              void* d_out, int out_size, void* d_ws, size_t ws_size,
                              hipStream_t stream) {
  const float* x = (const float*)d_in[0];
  const int* ei = (const int*)d_in[1];
  const int* et = (const int*)d_in[2];
  const int* batch = (const int*)d_in[3];
  const float* Wp = (const float*)d_in[4];
  const float* bp = (const float*)d_in[5];
  const float* rel_w = (const float*)d_in[6];
  const float* root_w = (const float*)d_in[7];
  const float* conv_b = (const float*)d_in[8];
  const float* ln_g = (const float*)d_in[9];
  const float* ln_b = (const float*)d_in[10];
  float* out = (float*)d_out;
  const int* srcv = ei;
  const int* dstv = ei + NE;

  const int NGRP = NN / 16;       // 3125 exact
  const int NGRP_PAD = NGRP + 3;  // GEMMs read up to group 3127 (guarded stores)

  char* w = (char*)d_ws;
  auto alloc = [&](size_t bytes) {
    char* p = w;
    w += (bytes + 255) & ~(size_t)255;
    return p;
  };
  float* h = (float*)alloc((size_t)NN * HID * 4);
  float* OUT = (float*)alloc((size_t)NN * HID * 4);
  float* winv = (float*)alloc((size_t)NN * NREL * 4);  // zero-span start
  int* deg = (int*)alloc((size_t)NN * 4);
  int* rowstart = (int*)alloc((size_t)(NN + 1) * 4);
  int* fillpos = (int*)alloc((size_t)NN * 4);
  char* zend = w;  // zero-span end
  int* pkd = (int*)alloc((size_t)NE * 4);
  float* wsc = (float*)alloc((size_t)NE * 4);
  int* partial = (int*)alloc(256 * 4);
  ushort* xh = (ushort*)alloc((size_t)NGRP_PAD * 1024 * 2);
  ushort* xl = (ushort*)alloc((size_t)NGRP_PAD * 1024 * 2);
  ushort* hh = (ushort*)alloc((size_t)NGRP_PAD * 2048 * 2);
  ushort* hl = (ushort*)alloc((size_t)NGRP_PAD * 2048 * 2);
  ushort* hb = (ushort*)alloc((size_t)NN * HID * 2);
  ushort* Wph = (ushort*)alloc((size_t)IND * HID * 2);
  ushort* Wpl = (ushort*)alloc((size_t)IND * HID * 2);
  ushort* Bp = (ushort*)alloc((size_t)NLAY * 2 * 196608 * 2);
  ushort* AGG = (ushort*)alloc((size_t)NGRP_PAD * 20480 * 2);

  const int NB_E = (NE + 255) / 256;
  const int NB_N = (NN + 255) / 256;
  const int MB = (NN + 127) / 128;   // 391 (projection grid y)
  const int MB2 = (NN + 63) / 64;    // 782 (gemm2 grid)
  const int ZSPAN = (int)((zend - (char*)winv) / 4);

  zero_kernel<<<dim3(1024), dim3(256), 0, stream>>>(winv, ZSPAN);
  zero_kernel<<<dim3(32), dim3(256), 0, stream>>>(out, NG * HID);

  count_edges<<<dim3(NB_E), dim3(256), 0, stream>>>(dstv, et, winv, deg);
  invert_winv<<<dim3((NN * NREL + 255) / 256), dim3(256), 0, stream>>>(winv);
  scan_block<<<dim3(NB_N), dim3(256), 0, stream>>>(deg, rowstart, partial);
  scan_partials<<<dim3(1), dim3(256), 0, stream>>>(partial, NB_N);
  scan_add<<<dim3(NB_N), dim3(256), 0, stream>>>(rowstart, partial);
  fill_csr<<<dim3(NB_E), dim3(256), 0, stream>>>(dstv, srcv, et, fillpos, rowstart,
                                                 winv, pkd, wsc);

  transpose_split_frag<<<dim3((IND * HID + 255) / 256), dim3(256), 0, stream>>>(
      Wp, Wph, Wpl, IND);
  pack_B<<<dim3((NLAY * 1536 * 128 + 255) / 256), dim3(256), 0, stream>>>(
      root_w, rel_w, Bp);

  split_frag<IND><<<dim3(NGRP), dim3(256), 0, stream>>>(x, xh, xl, (ushort*)nullptr);

  // projection: h = x @ Wp + bp (3-term)
  gemm_frag<IND><<<dim3(1, MB), dim3(256), 0, stream>>>(xh, xl, Wph, Wpl, bp, h, NN);
  split_frag<HID><<<dim3(NGRP), dim3(256), 0, stream>>>(h, hh, hl, hb);

  for (int l = 0; l < NLAY; ++l) {
    agg2<<<dim3(NGRP), dim3(256), 0, stream>>>(pkd, wsc, rowstart, hb, AGG);
    gemm2<<<dim3(MB2), dim3(256), 0, stream>>>(
        hh, hl, AGG, Bp + (size_t)l * 2 * 196608, conv_b + (size_t)l * HID, OUT, NN);
    ln2<<<dim3(NGRP), dim3(256), 0, stream>>>(
        OUT, h, ln_g + (size_t)l * HID, ln_b + (size_t)l * HID, hh, hl, hb,
        (l != NLAY - 1) ? 1 : 0);
  }

  pool_kernel<<<dim3((NN + 63) / 64), dim3(128), 0, stream>>>(h, batch, out);
}